// Round 15
// baseline (102.781 us; speedup 1.0000x reference)
//
#include <hip/hip_runtime.h>

#define N_SRC 8192
#define M_PTS 16384

constexpr int BLOCK = 256;
constexpr int PPT   = 8;               // query points per thread (4x float2)
constexpr int NV    = PPT / 2;         // v2f groups
constexpr int MTILE = BLOCK * PPT;     // 2048 points per block
constexpr int NCHUNKS = 256;           // source chunks (grid.y)
constexpr int SRC_PER_CHUNK = N_SRC / NCHUNKS;  // 32
// grid = (16384/2048) x 256 = 8 x 256 = 2048 blocks = 8 blocks/CU = 32 waves/CU
// = 8 waves/SIMD, enabled by the 64-VGPR cap from __launch_bounds__(256, 8).

typedef float v2f __attribute__((ext_vector_type(2)));

// Pack (x, y, z, r2) per source (wave-uniform -> s_load_dwordx4) plus a
// separate w = b/(2*pi) array. r2 matches the reference's
// jnp.sum(r_p*r_p, -1); the r2+q2-2*cross cancellation then tracks the
// reference up to dot-product rounding order (validated: absmax 0.125, pass).
__global__ void pack_sources(const float* __restrict__ b_n,
                             const float* __restrict__ r_p,
                             float4* __restrict__ packed,
                             float* __restrict__ wgt) {
    const float INV2PI = 0.15915494309189533577f;
    int s = blockIdx.x * blockDim.x + threadIdx.x;
    if (s < N_SRC) {
        float x = r_p[3 * s + 0];
        float y = r_p[3 * s + 1];
        float z = r_p[3 * s + 2];
        float r2 = x * x + y * y + z * z;
        packed[s] = make_float4(x, y, z, r2);
        wgt[s] = b_n[s] * INV2PI;
    }
}

// ATOMIC=false: write per-chunk partials to part[chunk][m] (plain stores).
// ATOMIC=true : atomicAdd into out (fallback when ws is too small).
template <bool ATOMIC>
__global__ __launch_bounds__(BLOCK, 8) void potential_kernel(
        const float4* __restrict__ src,
        const float*  __restrict__ wgt,
        const float*  __restrict__ coord,
        float*        __restrict__ outp) {
    const int t = threadIdx.x;
    const int m_base = blockIdx.x * MTILE;
    const int s_base = blockIdx.y * SRC_PER_CHUNK;

    const float CZ = 0.39894228040143267794f;  // 1/sqrt(2*pi)

    // element j of group h covers point p = 2*h + j
    v2f qx[NV], qy[NV], qz[NV], q2[NV], acc[NV];
#pragma unroll
    for (int h = 0; h < NV; ++h) {
#pragma unroll
        for (int j = 0; j < 2; ++j) {
            int m = m_base + (2 * h + j) * BLOCK + t;   // strided, coalesced
            float x = coord[3 * m + 0];
            float y = coord[3 * m + 1];
            float z = coord[3 * m + 2] + CZ;
            qx[h][j] = x;
            qy[h][j] = y;
            qz[h][j] = z;
            q2[h][j] = x * x + y * y + z * z;
        }
        acc[h] = (v2f){0.0f, 0.0f};
    }

    const v2f NEG2 = (v2f){-2.0f, -2.0f};
    const v2f ZERO = (v2f){0.0f, 0.0f};

#pragma unroll 2
    for (int i = 0; i < SRC_PER_CHUNK; ++i) {
        float4 sv = src[s_base + i];         // uniform -> s_load_dwordx4
        float  w  = wgt[s_base + i];         // uniform -> s_load_dword
        v2f sx = (v2f){sv.x, sv.x};
        v2f sy = (v2f){sv.y, sv.y};
        v2f sz = (v2f){sv.z, sv.z};
        v2f sr2 = (v2f){sv.w, sv.w};
        v2f wv = (v2f){w, w};
#pragma unroll
        for (int h = 0; h < NV; ++h) {
            // replicate reference: (r2 + q2) - 2*(r.q), clamped at 0.
            v2f cross = sx * qx[h];
            cross = __builtin_elementwise_fma(sy, qy[h], cross);
            cross = __builtin_elementwise_fma(sz, qz[h], cross);
            v2f t1 = q2[h] + sr2;
            // 2*cross is exact (pow2) -> fused sub == reference mul+sub
            v2f sq = __builtin_elementwise_fma(NEG2, cross, t1);
            sq = __builtin_elementwise_max(sq, ZERO);
            v2f r;
            r[0] = __builtin_amdgcn_rsqf(sq[0]);   // ~1 ulp hw rsq
            r[1] = __builtin_amdgcn_rsqf(sq[1]);
            acc[h] = __builtin_elementwise_fma(wv, r, acc[h]);
        }
    }

#pragma unroll
    for (int h = 0; h < NV; ++h) {
#pragma unroll
        for (int j = 0; j < 2; ++j) {
            int m = m_base + (2 * h + j) * BLOCK + t;
            if (ATOMIC) {
                atomicAdd(&outp[m], acc[h][j]);
            } else {
                outp[(size_t)blockIdx.y * M_PTS + m] = acc[h][j];
            }
        }
    }
}

__global__ __launch_bounds__(256) void reduce_partials(
        const float* __restrict__ part, float* __restrict__ out) {
    int m = blockIdx.x * 256 + threadIdx.x;
    float s = 0.0f;
#pragma unroll 8
    for (int c = 0; c < NCHUNKS; ++c)
        s += part[(size_t)c * M_PTS + m];
    out[m] = s;
}

extern "C" void kernel_launch(void* const* d_in, const int* in_sizes, int n_in,
                              void* d_out, int out_size, void* d_ws, size_t ws_size,
                              hipStream_t stream) {
    const float* b_n   = (const float*)d_in[0];
    const float* r_p   = (const float*)d_in[1];
    const float* coord = (const float*)d_in[2];
    float* out = (float*)d_out;

    float4* packed = (float4*)d_ws;
    float* wgt = (float*)((char*)d_ws + N_SRC * sizeof(float4));
    const size_t part_off = N_SRC * sizeof(float4) + N_SRC * sizeof(float); // 160 KB
    float* part = (float*)((char*)d_ws + part_off);
    const size_t need = part_off + (size_t)NCHUNKS * M_PTS * sizeof(float); // ~17 MB

    pack_sources<<<dim3((N_SRC + 255) / 256), dim3(256), 0, stream>>>(
        b_n, r_p, packed, wgt);

    if (ws_size >= need) {
        // partials + reduce: no atomics, deterministic per-m order
        potential_kernel<false><<<dim3(M_PTS / MTILE, NCHUNKS), dim3(BLOCK), 0, stream>>>(
            packed, wgt, coord, part);
        reduce_partials<<<dim3(M_PTS / 256), dim3(256), 0, stream>>>(part, out);
    } else {
        // fallback: zero out then atomic-combine
        hipMemsetAsync(d_out, 0, M_PTS * sizeof(float), stream);
        potential_kernel<true><<<dim3(M_PTS / MTILE, NCHUNKS), dim3(BLOCK), 0, stream>>>(
            packed, wgt, coord, out);
    }
}

// Round 16
// 90.291 us; speedup vs baseline: 1.1383x; 1.1383x over previous
//
#include <hip/hip_runtime.h>

#define N_SRC 8192
#define M_PTS 16384

constexpr int BLOCK = 256;
constexpr int PPT   = 8;               // query points per thread (4x float2)
constexpr int NV    = PPT / 2;         // v2f groups
constexpr int MTILE = BLOCK * PPT;     // 2048 points per block
constexpr int NCHUNKS = 128;           // source chunks (grid.y)
constexpr int SRC_PER_CHUNK = N_SRC / NCHUNKS;  // 64
// grid = (16384/2048) x 128 = 8 x 128 = 1024 blocks = 4 blocks/CU, 16 waves/CU

typedef float v2f __attribute__((ext_vector_type(2)));

// Fused: each block stages its chunk's 64 sources in LDS (computing
// r2 = x*x+y*y+z*z and w = b/(2*pi) in-place), then runs the pair loop
// reading LDS broadcasts. Per-pair math is bit-identical to the passing
// kernels: sq = (q2 + r2) - 2*cross via fma, clamped, v_rsq.
// ATOMIC=false: write per-chunk partials to part[chunk][m] (plain stores).
// ATOMIC=true : atomicAdd into out (fallback when ws is too small).
template <bool ATOMIC>
__global__ __launch_bounds__(BLOCK, 4) void potential_kernel(
        const float* __restrict__ b_n,
        const float* __restrict__ r_p,
        const float* __restrict__ coord,
        float*       __restrict__ outp) {
    const int t = threadIdx.x;
    const int m_base = blockIdx.x * MTILE;
    const int s_base = blockIdx.y * SRC_PER_CHUNK;

    const float CZ = 0.39894228040143267794f;     // 1/sqrt(2*pi)
    const float INV2PI = 0.15915494309189533577f; // 1/(2*pi)

    __shared__ float4 sA[SRC_PER_CHUNK];   // (x, y, z, r2)
    __shared__ float  sW[SRC_PER_CHUNK];   // b/(2*pi)
    if (t < SRC_PER_CHUNK) {
        int s = s_base + t;
        float x = r_p[3 * s + 0];
        float y = r_p[3 * s + 1];
        float z = r_p[3 * s + 2];
        float r2 = x * x + y * y + z * z;  // same expr as reference sum
        sA[t] = make_float4(x, y, z, r2);
        sW[t] = b_n[s] * INV2PI;
    }

    // element j of group h covers point p = 2*h + j
    v2f qx[NV], qy[NV], qz[NV], q2[NV], acc[NV];
#pragma unroll
    for (int h = 0; h < NV; ++h) {
#pragma unroll
        for (int j = 0; j < 2; ++j) {
            int m = m_base + (2 * h + j) * BLOCK + t;   // strided, coalesced
            float x = coord[3 * m + 0];
            float y = coord[3 * m + 1];
            float z = coord[3 * m + 2] + CZ;
            qx[h][j] = x;
            qy[h][j] = y;
            qz[h][j] = z;
            q2[h][j] = x * x + y * y + z * z;
        }
        acc[h] = (v2f){0.0f, 0.0f};
    }

    const v2f NEG2 = (v2f){-2.0f, -2.0f};
    const v2f ZERO = (v2f){0.0f, 0.0f};

    __syncthreads();

#pragma unroll 4
    for (int i = 0; i < SRC_PER_CHUNK; ++i) {
        float4 sv = sA[i];                   // ds_read_b128 broadcast
        float  w  = sW[i];                   // ds_read_b32 broadcast
        v2f sx = (v2f){sv.x, sv.x};
        v2f sy = (v2f){sv.y, sv.y};
        v2f sz = (v2f){sv.z, sv.z};
        v2f sr2 = (v2f){sv.w, sv.w};
        v2f wv = (v2f){w, w};
#pragma unroll
        for (int h = 0; h < NV; ++h) {
            // replicate reference: (r2 + q2) - 2*(r.q), clamped at 0.
            v2f cross = sx * qx[h];
            cross = __builtin_elementwise_fma(sy, qy[h], cross);
            cross = __builtin_elementwise_fma(sz, qz[h], cross);
            v2f t1 = q2[h] + sr2;
            // 2*cross is exact (pow2) -> fused sub == reference mul+sub
            v2f sq = __builtin_elementwise_fma(NEG2, cross, t1);
            sq = __builtin_elementwise_max(sq, ZERO);
            v2f r;
            r[0] = __builtin_amdgcn_rsqf(sq[0]);   // ~1 ulp hw rsq
            r[1] = __builtin_amdgcn_rsqf(sq[1]);
            acc[h] = __builtin_elementwise_fma(wv, r, acc[h]);
        }
    }

#pragma unroll
    for (int h = 0; h < NV; ++h) {
#pragma unroll
        for (int j = 0; j < 2; ++j) {
            int m = m_base + (2 * h + j) * BLOCK + t;
            if (ATOMIC) {
                atomicAdd(&outp[m], acc[h][j]);
            } else {
                outp[(size_t)blockIdx.y * M_PTS + m] = acc[h][j];
            }
        }
    }
}

__global__ __launch_bounds__(256) void reduce_partials(
        const float* __restrict__ part, float* __restrict__ out) {
    int m = blockIdx.x * 256 + threadIdx.x;
    float s = 0.0f;
#pragma unroll 8
    for (int c = 0; c < NCHUNKS; ++c)
        s += part[(size_t)c * M_PTS + m];
    out[m] = s;
}

extern "C" void kernel_launch(void* const* d_in, const int* in_sizes, int n_in,
                              void* d_out, int out_size, void* d_ws, size_t ws_size,
                              hipStream_t stream) {
    const float* b_n   = (const float*)d_in[0];
    const float* r_p   = (const float*)d_in[1];
    const float* coord = (const float*)d_in[2];
    float* out = (float*)d_out;

    float* part = (float*)d_ws;
    const size_t need = (size_t)NCHUNKS * M_PTS * sizeof(float); // ~8.4 MB

    if (ws_size >= need) {
        // partials + reduce: no atomics, deterministic per-m order
        potential_kernel<false><<<dim3(M_PTS / MTILE, NCHUNKS), dim3(BLOCK), 0, stream>>>(
            b_n, r_p, coord, part);
        reduce_partials<<<dim3(M_PTS / 256), dim3(256), 0, stream>>>(part, out);
    } else {
        // fallback: zero out then atomic-combine
        hipMemsetAsync(d_out, 0, M_PTS * sizeof(float), stream);
        potential_kernel<true><<<dim3(M_PTS / MTILE, NCHUNKS), dim3(BLOCK), 0, stream>>>(
            b_n, r_p, coord, out);
    }
}